// Round 2
// baseline (401.931 us; speedup 1.0000x reference)
//
#include <hip/hip_runtime.h>
#include <hip/hip_bf16.h>

typedef unsigned short u16;
typedef unsigned int u32;
typedef __bf16 bf16x8 __attribute__((ext_vector_type(8)));
typedef float f32x4 __attribute__((ext_vector_type(4)));
typedef unsigned int u32x4 __attribute__((ext_vector_type(4)));

// ---------------- constants ----------------
#define BATCH 8
#define SEQ   2048
#define DIM   1024
#define M_TOT (BATCH * SEQ)      // 16384
#define N_QKV (3 * DIM)          // 3072

// workspace layout (bytes) — peak 201,326,592 (192 MiB)
//   [0, 100663296)            qkv bf16 (16384 x 3072)
//   [100663296, 134217728)    vt  bf16 (8 x 1024 x 2048)
//   [134217728, ...)          region C, time-multiplexed:
//       phase 1: xb bf16 (33,554,432) + wt bf16 (6,291,456)   [dead after QKV GEMM]
//       phase 2: S/P bf16 (8 x 2048 x 2048 x 2 = 67,108,864)  [softmax in-place]
#define OFF_QKV  ((size_t)0)
#define OFF_VT   ((size_t)100663296)
#define OFF_C    ((size_t)134217728)
#define OFF_XB   OFF_C
#define OFF_WT   (OFF_C + (size_t)33554432)
#define OFF_S    OFF_C

__device__ __forceinline__ u16 f32_to_bf16(float f) {
    u32 u = __builtin_bit_cast(u32, f);
    u = (u + 0x7fffu + ((u >> 16) & 1u)) >> 16;
    return (u16)u;
}

__device__ __forceinline__ float bf16_to_f32(u16 h) {
    u32 u = ((u32)h) << 16;
    return __builtin_bit_cast(float, u);
}

__device__ __forceinline__ bf16x8 lds_load8(const u16* p) {
    return __builtin_bit_cast(bf16x8, *(const u32x4*)p);
}

// ================= 256x256 / BK=64 deep-pipelined GEMM core =================
// 512 threads = 8 waves (2 M x 4 N), per-wave 128x64 output = acc[8][4] of
// 16x16x32 bf16 MFMA fragments.
//
// LDS = 8 units of 16 KiB (256 rows x 32 bf16): units 0..3 = A, 4..7 = B.
// Unit for K-tile t, K-half ks lives in slot (t&1)*2 + ks  (double buffer).
//
// Swizzle (T2): within a unit, the 16B chunk for (row, kchunk kg) is stored
// at chunk index row*4 + (kg ^ (row&3)).  Fragment reads (lane -> row
// frag+lane&15, kg = lane>>4) then hit bank-quad residue
// 4*(lane&1) + ((lane>>4) ^ (lane&3)), which covers each of the 8 residues
// exactly 8 times per wave -> conflict-free b128 reads.
// global_load_lds needs a linear LDS dest, so the *source* address is
// pre-swizzled instead (both-sides-or-neither rule).
#define UNIT 8192  // u16 elements per 16 KiB unit

__device__ __forceinline__ void stage_unit(const u16* g, size_t lda, int k0,
                                           u16* lds, int tid) {
    int wv = tid >> 6;
#pragma unroll
    for (int iss = 0; iss < 2; ++iss) {
        int s = iss * 512 + tid;            // chunk slot 0..1023
        int row = s >> 2;                   // 4 chunks per 32-wide row
        int kg = (s & 3) ^ (row & 3);       // inverse-swizzled k-group
        const u16* gp = g + (size_t)row * lda + (k0 + (kg << 3));
        u16* lp = lds + (size_t)(iss * 512 + wv * 64) * 8;  // wave-uniform base
        __builtin_amdgcn_global_load_lds((const __attribute__((address_space(1))) void*)gp,
                                         (__attribute__((address_space(3))) void*)lp,
                                         16, 0, 0);
    }
}

// One phase: 8 x ds_read_b128 + 16 MFMA (C-half MH x one K-half unit).
template <int MH>
__device__ __forceinline__ void mfma_phase(const u16* uA, const u16* uB, int lane,
                                           int wm, int wn, f32x4 acc[8][4]) {
    int lrow = lane & 15;
    int off = (((lane >> 4) ^ (lane & 3)) << 3);   // swizzled k-offset (elems)
    bf16x8 a[4], b[4];
#pragma unroll
    for (int i = 0; i < 4; ++i) {
        a[i] = lds_load8(&uA[(wm * 128 + (MH * 4 + i) * 16 + lrow) * 32 + off]);
        b[i] = lds_load8(&uB[(wn * 64 + i * 16 + lrow) * 32 + off]);
    }
    __builtin_amdgcn_s_setprio(1);
#pragma unroll
    for (int i = 0; i < 4; ++i)
#pragma unroll
        for (int j = 0; j < 4; ++j)
            acc[MH * 4 + i][j] =
                __builtin_amdgcn_mfma_f32_16x16x32_bf16(a[i], b[j], acc[MH * 4 + i][j], 0, 0, 0);
    __builtin_amdgcn_s_setprio(0);
}

// Pipelined main loop.  Issue order per K-tile t: P1 A(t+1,ks0), P2 B(t+1,ks0),
// P3 A(t+1,ks1), P4 B(t+1,ks1) -> entering a tile there are always 8 loads
// (4 units) in flight; counted vmcnt(4) retires exactly the two units the
// next two phases read.  vmcnt never drains to 0 in steady state (T3+T4).
// Raw s_barrier (NOT __syncthreads -> would emit vmcnt(0) and kill the
// pipeline).  All branches are wave-uniform; every wave executes the same
// barrier count.
__device__ __forceinline__ void gemm_block_256(const u16* __restrict__ A, size_t lda,
                                               const u16* __restrict__ B, size_t ldb,
                                               int KT, u16* lds, int tid,
                                               f32x4 acc[8][4]) {
    int lane = tid & 63;
    int wv = tid >> 6;
    int wm = wv >> 2, wn = wv & 3;
    // prologue: both K-halves of tile 0
    stage_unit(A, lda, 0,  lds + 0 * UNIT, tid);
    stage_unit(B, ldb, 0,  lds + 4 * UNIT, tid);
    stage_unit(A, lda, 32, lds + 1 * UNIT, tid);
    stage_unit(B, ldb, 32, lds + 5 * UNIT, tid);
    for (int t = 0; t < KT; ++t) {
        int p = t & 1, pn = p ^ 1;
        int kb = (t + 1) << 6;
        bool pf = (t + 1 < KT);
        // W0: retire A(t,0),B(t,0); A(t,1),B(t,1) stay in flight
        asm volatile("s_waitcnt vmcnt(4)" ::: "memory");
        __builtin_amdgcn_s_barrier();
        // P1
        if (pf) stage_unit(A, lda, kb, lds + (size_t)(pn * 2) * UNIT, tid);
        mfma_phase<0>(lds + (size_t)(p * 2) * UNIT, lds + (size_t)(4 + p * 2) * UNIT,
                      lane, wm, wn, acc);
        __builtin_amdgcn_s_barrier();
        // P2
        if (pf) stage_unit(B, ldb, kb, lds + (size_t)(4 + pn * 2) * UNIT, tid);
        mfma_phase<1>(lds + (size_t)(p * 2) * UNIT, lds + (size_t)(4 + p * 2) * UNIT,
                      lane, wm, wn, acc);
        __builtin_amdgcn_s_barrier();
        // W1: retire A(t,1),B(t,1); A(t+1,0),B(t+1,0) stay in flight
        if (pf) { asm volatile("s_waitcnt vmcnt(4)" ::: "memory"); }
        else    { asm volatile("s_waitcnt vmcnt(0)" ::: "memory"); }
        __builtin_amdgcn_s_barrier();
        // P3
        if (pf) stage_unit(A, lda, kb + 32, lds + (size_t)(pn * 2 + 1) * UNIT, tid);
        mfma_phase<0>(lds + (size_t)(p * 2 + 1) * UNIT, lds + (size_t)(4 + p * 2 + 1) * UNIT,
                      lane, wm, wn, acc);
        __builtin_amdgcn_s_barrier();
        // P4
        if (pf) stage_unit(B, ldb, kb + 32, lds + (size_t)(4 + pn * 2 + 1) * UNIT, tid);
        mfma_phase<1>(lds + (size_t)(p * 2 + 1) * UNIT, lds + (size_t)(4 + p * 2 + 1) * UNIT,
                      lane, wm, wn, acc);
        // next iteration's W0 wait+barrier closes the tile
    }
}

// ---------------- kernel 1: cast x fp32 -> bf16 ----------------
__global__ __launch_bounds__(256) void cast_x_kernel(const float* __restrict__ x,
                                                     u16* __restrict__ xb) {
    size_t g = (size_t)blockIdx.x * 256 + threadIdx.x;   // group of 4 elems
    f32x4 v = ((const f32x4*)x)[g];
    u16 o[4] = {f32_to_bf16(v.x), f32_to_bf16(v.y), f32_to_bf16(v.z), f32_to_bf16(v.w)};
    *(unsigned long long*)(xb + g * 4) = *(const unsigned long long*)o;
}

// ---------------- kernel 2: transpose-cast W [k][n] fp32 -> Wt [n][k] bf16 ----------------
__global__ __launch_bounds__(256) void transpose_w_kernel(const float* __restrict__ wq,
                                                          const float* __restrict__ wk,
                                                          const float* __restrict__ wv,
                                                          u16* __restrict__ wt) {
    __shared__ __align__(16) u16 tile[64][80];
    const float* w = blockIdx.z == 0 ? wq : (blockIdx.z == 1 ? wk : wv);
    int k0 = blockIdx.x * 64, n0 = blockIdx.y * 64;
    for (int g = threadIdx.x; g < 1024; g += 256) {
        int r = g >> 4, c = (g & 15) << 2;
        f32x4 v = *(const f32x4*)(w + (size_t)(k0 + r) * 1024 + n0 + c);
        tile[r][c + 0] = f32_to_bf16(v.x);
        tile[r][c + 1] = f32_to_bf16(v.y);
        tile[r][c + 2] = f32_to_bf16(v.z);
        tile[r][c + 3] = f32_to_bf16(v.w);
    }
    __syncthreads();
    u16* out = wt + (size_t)blockIdx.z * 1024 * 1024;
    for (int g = threadIdx.x; g < 512; g += 256) {
        int nr = g >> 3, kc = (g & 7) << 3;
        __align__(16) u16 tmp[8];
#pragma unroll
        for (int i = 0; i < 8; ++i) tmp[i] = tile[kc + i][nr];
        *(u32x4*)(out + (size_t)(n0 + nr) * 1024 + k0 + kc) = *(const u32x4*)tmp;
    }
}

// ---------------- kernel 3: QKV GEMM (256^2 pipelined): qkv[m][n'] = xb[m][:] . wt[n'][:] ----
__global__ __launch_bounds__(512, 2) void gemm_qkv_kernel(const u16* __restrict__ xb,
                                                          const u16* __restrict__ wt,
                                                          u16* __restrict__ qkv) {
    __shared__ __align__(16) u16 lds[8 * UNIT];
    // XCD-aware swizzle (T1): 768 % 8 == 0, simple variant is bijective
    int wg = blockIdx.x;
    int qx = gridDim.x >> 3;
    int swz = (wg & 7) * qx + (wg >> 3);
    int mt = swz / 12, nt = swz - mt * 12;   // nt fastest: A-panel L2 reuse per XCD
    const u16* A = xb + (size_t)mt * 256 * 1024;
    const u16* B = wt + (size_t)nt * 256 * 1024;
    int tid = threadIdx.x;
    f32x4 acc[8][4] = {};
    gemm_block_256(A, 1024, B, 1024, 16, lds, tid, acc);
    int lane = tid & 63, wv = tid >> 6;
    int wm = wv >> 2, wn = wv & 3;
    int r0 = (lane >> 4) << 2, c0 = lane & 15;
    size_t mbase = (size_t)mt * 256 + wm * 128;
    int nbase = nt * 256 + wn * 64;
#pragma unroll
    for (int i = 0; i < 8; ++i)
#pragma unroll
        for (int j = 0; j < 4; ++j) {
            int col = nbase + j * 16 + c0;
            float scale = (col < 1024) ? 0.03125f : 1.0f;  // fold 1/sqrt(1024) into Q
#pragma unroll
            for (int r = 0; r < 4; ++r) {
                size_t row = mbase + i * 16 + r0 + r;
                qkv[row * (size_t)N_QKV + col] = f32_to_bf16(acc[i][j][r] * scale);
            }
        }
}

// ---------------- kernel 4: transpose V -> Vt [b][d][m] ----------------
__global__ __launch_bounds__(256) void transpose_v_kernel(const u16* __restrict__ qkv,
                                                          u16* __restrict__ vt) {
    __shared__ __align__(16) u16 tile[64][80];
    int m0 = blockIdx.x * 64, d0 = blockIdx.y * 64, b = blockIdx.z;
    const u16* src = qkv + (size_t)b * SEQ * N_QKV + 2048;  // V columns
    for (int g = threadIdx.x; g < 512; g += 256) {
        int r = g >> 3, c = (g & 7) << 3;
        *(u32x4*)&tile[r][c] = *(const u32x4*)(src + (size_t)(m0 + r) * N_QKV + d0 + c);
    }
    __syncthreads();
    u16* dst = vt + (size_t)b * DIM * SEQ;
    for (int g = threadIdx.x; g < 512; g += 256) {
        int dr = g >> 3, mc = (g & 7) << 3;
        __align__(16) u16 tmp[8];
#pragma unroll
        for (int i = 0; i < 8; ++i) tmp[i] = tile[mc + i][dr];
        *(u32x4*)(dst + (size_t)(d0 + dr) * SEQ + m0 + mc) = *(const u32x4*)tmp;
    }
}

// ---------------- kernel 5: S = Q . K^T, triangular 256-tile grid, bf16 out ----------------
__global__ __launch_bounds__(512, 2) void gemm_scores_kernel(const u16* __restrict__ qkv,
                                                             u16* __restrict__ S) {
    __shared__ __align__(16) u16 lds[8 * UNIT];
    int t = blockIdx.x;      // 0..35 triangular index over 8x8 256-tiles
    int b = blockIdx.y;
    // bounded integer triangular decomposition (no FP, <= 7 iterations)
    int ntile = 0;
#pragma unroll
    for (int it = 1; it < 8; ++it)
        if ((it * (it + 1)) / 2 <= t) ntile = it;
    int mtile = t - (ntile * (ntile + 1)) / 2;   // 0 <= mtile <= ntile
    const u16* A = qkv + (size_t)b * SEQ * N_QKV + (size_t)ntile * 256 * N_QKV;        // Q rows
    const u16* B = qkv + (size_t)b * SEQ * N_QKV + (size_t)mtile * 256 * N_QKV + 1024; // K rows
    int tid = threadIdx.x;
    f32x4 acc[8][4] = {};
    gemm_block_256(A, N_QKV, B, N_QKV, 16, lds, tid, acc);
    u16* out = S + (size_t)b * SEQ * SEQ + (size_t)ntile * 256 * SEQ + (size_t)mtile * 256;
    int lane = tid & 63, wv = tid >> 6;
    int wm = wv >> 2, wn = wv & 3;
    int r0 = (lane >> 4) << 2, c0 = lane & 15;
#pragma unroll
    for (int i = 0; i < 8; ++i)
#pragma unroll
        for (int j = 0; j < 4; ++j) {
            int col = wn * 64 + j * 16 + c0;
#pragma unroll
            for (int r = 0; r < 4; ++r) {
                int row = wm * 128 + i * 16 + r0 + r;
                out[(size_t)row * SEQ + col] = f32_to_bf16(acc[i][j][r]);
            }
        }
}

// ---------------- kernel 6: row softmax over bf16 S, in-place, register-resident ----
__global__ __launch_bounds__(256) void softmax_kernel(u16* __restrict__ SP) {
    int gr = blockIdx.x;
    int n = gr & 2047;
    u16* s = SP + (size_t)gr * SEQ;
    __shared__ float red[4];
    int t = threadIdx.x;
    int base = t << 3;
    int len = n + 1;
    float v[8];
    float lmax = -3.0e38f;
    if (base < len) {
        u32x4 raw = *(const u32x4*)(s + base);
        const u16* h = (const u16*)&raw;
#pragma unroll
        for (int i = 0; i < 8; ++i) {
            v[i] = (base + i < len) ? bf16_to_f32(h[i]) : -3.0e38f;
            lmax = fmaxf(lmax, v[i]);
        }
    } else {
#pragma unroll
        for (int i = 0; i < 8; ++i) v[i] = -3.0e38f;
    }
#pragma unroll
    for (int off = 32; off; off >>= 1) lmax = fmaxf(lmax, __shfl_xor(lmax, off, 64));
    if ((t & 63) == 0) red[t >> 6] = lmax;
    __syncthreads();
    float gmax = fmaxf(fmaxf(red[0], red[1]), fmaxf(red[2], red[3]));
    __syncthreads();   // everyone has gmax before red is reused
    float lsum = 0.f;
#pragma unroll
    for (int i = 0; i < 8; ++i) {
        float e = __expf(v[i] - gmax);   // masked lanes -> exp(-huge) = 0
        v[i] = e;
        lsum += e;
    }
#pragma unroll
    for (int off = 32; off; off >>= 1) lsum += __shfl_xor(lsum, off, 64);
    if ((t & 63) == 0) red[t >> 6] = lsum;
    __syncthreads();
    float inv = 1.0f / (red[0] + red[1] + red[2] + red[3]);
    __align__(16) u16 o[8];
#pragma unroll
    for (int i = 0; i < 8; ++i) o[i] = f32_to_bf16(v[i] * inv);  // masked lanes write 0
    *(u32x4*)(s + base) = *(const u32x4*)o;
}

// ---------------- kernel 7: O = P . V (via Vt), causal K truncation, 256^2 ----------------
// ntile reversed so the longest blocks (KT=32) dispatch first (tail balance).
__global__ __launch_bounds__(512, 2) void gemm_out_kernel(const u16* __restrict__ P,
                                                          const u16* __restrict__ vt,
                                                          float* __restrict__ O) {
    __shared__ __align__(16) u16 lds[8 * UNIT];
    int dt = blockIdx.x, b = blockIdx.z;
    int ntile = (SEQ / 256 - 1) - blockIdx.y;
    const u16* A = P + (size_t)b * SEQ * SEQ + (size_t)ntile * 256 * SEQ;
    const u16* B = vt + (size_t)b * DIM * SEQ + (size_t)dt * 256 * SEQ;
    int tid = threadIdx.x;
    f32x4 acc[8][4] = {};
    int KT = (ntile + 1) * 4;  // keys beyond (ntile+1)*256 have P == 0
    gemm_block_256(A, SEQ, B, SEQ, KT, lds, tid, acc);
    float* out = O + (size_t)b * SEQ * DIM + (size_t)ntile * 256 * DIM + (size_t)dt * 256;
    int lane = tid & 63, wv = tid >> 6;
    int wm = wv >> 2, wn = wv & 3;
    int r0 = (lane >> 4) << 2, c0 = lane & 15;
#pragma unroll
    for (int i = 0; i < 8; ++i)
#pragma unroll
        for (int j = 0; j < 4; ++j) {
            int col = wn * 64 + j * 16 + c0;
#pragma unroll
            for (int r = 0; r < 4; ++r) {
                int row = wm * 128 + i * 16 + r0 + r;
                out[(size_t)row * DIM + col] = acc[i][j][r];
            }
        }
}

extern "C" void kernel_launch(void* const* d_in, const int* in_sizes, int n_in,
                              void* d_out, int out_size, void* d_ws, size_t ws_size,
                              hipStream_t stream) {
    const float* x = (const float*)d_in[0];
    const float* wq = (const float*)d_in[1];
    const float* wk = (const float*)d_in[2];
    const float* wv = (const float*)d_in[3];
    char* ws = (char*)d_ws;
    u16* qkv = (u16*)(ws + OFF_QKV);
    u16* vt = (u16*)(ws + OFF_VT);
    u16* xb = (u16*)(ws + OFF_XB);
    u16* wt = (u16*)(ws + OFF_WT);
    u16* S = (u16*)(ws + OFF_S);   // aliases xb/wt region (dead by then)
    float* O = (float*)d_out;

    cast_x_kernel<<<M_TOT * DIM / 4 / 256, 256, 0, stream>>>(x, xb);
    transpose_w_kernel<<<dim3(16, 16, 3), 256, 0, stream>>>(wq, wk, wv, wt);
    gemm_qkv_kernel<<<(M_TOT / 256) * (N_QKV / 256), 512, 0, stream>>>(xb, wt, qkv);
    transpose_v_kernel<<<dim3(SEQ / 64, DIM / 64, BATCH), 256, 0, stream>>>(qkv, vt);
    gemm_scores_kernel<<<dim3(36, BATCH), 512, 0, stream>>>(qkv, S);
    softmax_kernel<<<BATCH * SEQ, 256, 0, stream>>>(S);
    gemm_out_kernel<<<dim3(DIM / 256, SEQ / 256, BATCH), 512, 0, stream>>>(S, vt, O);
}

// Round 3
// 386.293 us; speedup vs baseline: 1.0405x; 1.0405x over previous
//
#include <hip/hip_runtime.h>
#include <hip/hip_bf16.h>

typedef unsigned short u16;
typedef unsigned int u32;
typedef __bf16 bf16x8 __attribute__((ext_vector_type(8)));
typedef float f32x4 __attribute__((ext_vector_type(4)));
typedef unsigned int u32x4 __attribute__((ext_vector_type(4)));

// ---------------- constants ----------------
#define BATCH 8
#define SEQ   2048
#define DIM   1024
#define M_TOT (BATCH * SEQ)      // 16384
#define N_QKV (3 * DIM)          // 3072

// workspace layout (bytes) — peak 201,326,592 (192 MiB)
//   [0, 100663296)            qkv bf16 (16384 x 3072)
//   [100663296, 134217728)    vt  bf16 (8 x 1024 x 2048)
//   [134217728, ...)          region C, time-multiplexed:
//       phase 1: xb bf16 (33,554,432) + wt bf16 (6,291,456)   [dead after QKV GEMM]
//       phase 2: S/P bf16 (8 x 2048 x 2048 x 2 = 67,108,864)  [softmax in-place]
#define OFF_QKV  ((size_t)0)
#define OFF_VT   ((size_t)100663296)
#define OFF_C    ((size_t)134217728)
#define OFF_XB   OFF_C
#define OFF_WT   (OFF_C + (size_t)33554432)
#define OFF_S    OFF_C

__device__ __forceinline__ u16 f32_to_bf16(float f) {
    u32 u = __builtin_bit_cast(u32, f);
    u = (u + 0x7fffu + ((u >> 16) & 1u)) >> 16;
    return (u16)u;
}

__device__ __forceinline__ float bf16_to_f32(u16 h) {
    u32 u = ((u32)h) << 16;
    return __builtin_bit_cast(float, u);
}

__device__ __forceinline__ bf16x8 lds_load8(const u16* p) {
    return __builtin_bit_cast(bf16x8, *(const u32x4*)p);
}

// ================= 256x256 / BK=64 deep-pipelined GEMM core =================
// 512 threads = 8 waves (2 M x 4 N), per-wave 128x64 output = acc[8][4] of
// 16x16x32 bf16 MFMA fragments.
//
// LDS = 8 units of 16 KiB (256 rows x 32 bf16): units 0..3 = A, 4..7 = B.
// Unit for K-tile t, K-half ks lives in slot (t&1)*2 + ks  (double buffer).
//
// Swizzle (T2, round-3 fix): rows are 64 B = 4 chunks, so the bank-quad field
// (3 bits) needs 3 bits of row mixed in.  Chunk (row, kg) is stored at
//   slot = (row>>3)*32 + 8*((row>>1)&3) + ((row + 2*kg) & 7)
// Bijective: parity of the quad term recovers row&1; 2*kg walks the 4
// same-parity quads.  Fragment reads (lane -> row R0+lrow, kg = lane>>4)
// hit bank-quad (lrow + 2*kgl) & 7 — DISTINCT across every 8-lane group
// (rows +0..7 at fixed kg -> quads r+c mod 8), i.e. conflict-free b128.
// Round-2's slot = row*4 + (kg ^ (row&3)) gave only 4 distinct quads per
// 8-lane group (2-way conflict, measured 12.6M conflict cycles).
// global_load_lds writes linearly (lane&7 -> distinct quads, conflict-free),
// so the *global source* applies the inverse permutation.
#define UNIT 8192  // u16 elements per 16 KiB unit

__device__ __forceinline__ void stage_unit(const u16* g, size_t lda, int k0,
                                           u16* lds, int tid) {
    int wv = tid >> 6;
#pragma unroll
    for (int iss = 0; iss < 2; ++iss) {
        int s = iss * 512 + tid;            // linear chunk slot 0..1023
        // invert slot -> (row, kg)
        int o = s & 31;
        int p = o >> 3;                     // (row>>1)&3
        int q = o & 7;                      // (row + 2*kg)&7
        int row = ((s >> 5) << 3) + (p << 1) + (q & 1);
        int kg = ((q - (p << 1) - (q & 1)) & 7) >> 1;
        const u16* gp = g + (size_t)row * lda + (k0 + (kg << 3));
        u16* lp = lds + (size_t)(iss * 512 + wv * 64) * 8;  // wave-uniform base
        __builtin_amdgcn_global_load_lds((const __attribute__((address_space(1))) void*)gp,
                                         (__attribute__((address_space(3))) void*)lp,
                                         16, 0, 0);
    }
}

// One phase: 8 x ds_read_b128 + 16 MFMA (C-half MH x one K-half unit).
// Fragment base rows are multiples of 16, so only lrow/kgl enter the
// low slot fields; the row-block term is (R0>>3 + lrow>>3)*256 elems.
template <int MH>
__device__ __forceinline__ void mfma_phase(const u16* uA, const u16* uB, int lane,
                                           int wm, int wn, f32x4 acc[8][4]) {
    int lrow = lane & 15;
    int kgl = lane >> 4;
    int rb = lrow >> 3;
    int base_l = ((lrow >> 1) & 3) * 64 + ((lrow + 2 * kgl) & 7) * 8;
    bf16x8 a[4], b[4];
#pragma unroll
    for (int i = 0; i < 4; ++i) {
        a[i] = lds_load8(&uA[(size_t)((wm * 16 + (MH * 4 + i) * 2 + rb) * 256 + base_l)]);
        b[i] = lds_load8(&uB[(size_t)((wn * 8 + i * 2 + rb) * 256 + base_l)]);
    }
    __builtin_amdgcn_s_setprio(1);
#pragma unroll
    for (int i = 0; i < 4; ++i)
#pragma unroll
        for (int j = 0; j < 4; ++j)
            acc[MH * 4 + i][j] =
                __builtin_amdgcn_mfma_f32_16x16x32_bf16(a[i], b[j], acc[MH * 4 + i][j], 0, 0, 0);
    __builtin_amdgcn_s_setprio(0);
}

// Pipelined main loop.  Issue order per K-tile t: P1 A(t+1,ks0), P2 B(t+1,ks0),
// P3 A(t+1,ks1), P4 B(t+1,ks1) -> entering a tile there are always 8 loads
// (4 units) in flight; counted vmcnt(4) retires exactly the two units the
// next two phases read.  vmcnt never drains to 0 in steady state (T3+T4).
// Raw s_barrier (NOT __syncthreads -> would emit vmcnt(0) and kill the
// pipeline).  All branches are wave-uniform; every wave executes the same
// barrier count.
__device__ __forceinline__ void gemm_block_256(const u16* __restrict__ A, size_t lda,
                                               const u16* __restrict__ B, size_t ldb,
                                               int KT, u16* lds, int tid,
                                               f32x4 acc[8][4]) {
    int lane = tid & 63;
    int wv = tid >> 6;
    int wm = wv >> 2, wn = wv & 3;
    // prologue: both K-halves of tile 0
    stage_unit(A, lda, 0,  lds + 0 * UNIT, tid);
    stage_unit(B, ldb, 0,  lds + 4 * UNIT, tid);
    stage_unit(A, lda, 32, lds + 1 * UNIT, tid);
    stage_unit(B, ldb, 32, lds + 5 * UNIT, tid);
    for (int t = 0; t < KT; ++t) {
        int p = t & 1, pn = p ^ 1;
        int kb = (t + 1) << 6;
        bool pf = (t + 1 < KT);
        // W0: retire A(t,0),B(t,0); A(t,1),B(t,1) stay in flight
        asm volatile("s_waitcnt vmcnt(4)" ::: "memory");
        __builtin_amdgcn_s_barrier();
        // P1
        if (pf) stage_unit(A, lda, kb, lds + (size_t)(pn * 2) * UNIT, tid);
        mfma_phase<0>(lds + (size_t)(p * 2) * UNIT, lds + (size_t)(4 + p * 2) * UNIT,
                      lane, wm, wn, acc);
        __builtin_amdgcn_s_barrier();
        // P2
        if (pf) stage_unit(B, ldb, kb, lds + (size_t)(4 + pn * 2) * UNIT, tid);
        mfma_phase<1>(lds + (size_t)(p * 2) * UNIT, lds + (size_t)(4 + p * 2) * UNIT,
                      lane, wm, wn, acc);
        __builtin_amdgcn_s_barrier();
        // W1: retire A(t,1),B(t,1); A(t+1,0),B(t+1,0) stay in flight
        if (pf) { asm volatile("s_waitcnt vmcnt(4)" ::: "memory"); }
        else    { asm volatile("s_waitcnt vmcnt(0)" ::: "memory"); }
        __builtin_amdgcn_s_barrier();
        // P3
        if (pf) stage_unit(A, lda, kb + 32, lds + (size_t)(pn * 2 + 1) * UNIT, tid);
        mfma_phase<0>(lds + (size_t)(p * 2 + 1) * UNIT, lds + (size_t)(4 + p * 2 + 1) * UNIT,
                      lane, wm, wn, acc);
        __builtin_amdgcn_s_barrier();
        // P4
        if (pf) stage_unit(B, ldb, kb + 32, lds + (size_t)(4 + pn * 2 + 1) * UNIT, tid);
        mfma_phase<1>(lds + (size_t)(p * 2 + 1) * UNIT, lds + (size_t)(4 + p * 2 + 1) * UNIT,
                      lane, wm, wn, acc);
        // next iteration's W0 wait+barrier closes the tile
    }
}

// ---------------- kernel 1: cast x fp32 -> bf16 ----------------
__global__ __launch_bounds__(256) void cast_x_kernel(const float* __restrict__ x,
                                                     u16* __restrict__ xb) {
    size_t g = (size_t)blockIdx.x * 256 + threadIdx.x;   // group of 4 elems
    f32x4 v = ((const f32x4*)x)[g];
    u16 o[4] = {f32_to_bf16(v.x), f32_to_bf16(v.y), f32_to_bf16(v.z), f32_to_bf16(v.w)};
    *(unsigned long long*)(xb + g * 4) = *(const unsigned long long*)o;
}

// ---------------- kernel 2: transpose-cast W [k][n] fp32 -> Wt [n][k] bf16 ----------------
__global__ __launch_bounds__(256) void transpose_w_kernel(const float* __restrict__ wq,
                                                          const float* __restrict__ wk,
                                                          const float* __restrict__ wv,
                                                          u16* __restrict__ wt) {
    __shared__ __align__(16) u16 tile[64][80];
    const float* w = blockIdx.z == 0 ? wq : (blockIdx.z == 1 ? wk : wv);
    int k0 = blockIdx.x * 64, n0 = blockIdx.y * 64;
    for (int g = threadIdx.x; g < 1024; g += 256) {
        int r = g >> 4, c = (g & 15) << 2;
        f32x4 v = *(const f32x4*)(w + (size_t)(k0 + r) * 1024 + n0 + c);
        tile[r][c + 0] = f32_to_bf16(v.x);
        tile[r][c + 1] = f32_to_bf16(v.y);
        tile[r][c + 2] = f32_to_bf16(v.z);
        tile[r][c + 3] = f32_to_bf16(v.w);
    }
    __syncthreads();
    u16* out = wt + (size_t)blockIdx.z * 1024 * 1024;
    for (int g = threadIdx.x; g < 512; g += 256) {
        int nr = g >> 3, kc = (g & 7) << 3;
        __align__(16) u16 tmp[8];
#pragma unroll
        for (int i = 0; i < 8; ++i) tmp[i] = tile[kc + i][nr];
        *(u32x4*)(out + (size_t)(n0 + nr) * 1024 + k0 + kc) = *(const u32x4*)tmp;
    }
}

// ---------------- kernel 3: QKV GEMM (256^2 pipelined): qkv[m][n'] = xb[m][:] . wt[n'][:] ----
__global__ __launch_bounds__(512, 2) void gemm_qkv_kernel(const u16* __restrict__ xb,
                                                          const u16* __restrict__ wt,
                                                          u16* __restrict__ qkv) {
    __shared__ __align__(16) u16 lds[8 * UNIT];
    // XCD-aware swizzle (T1): 768 % 8 == 0, simple variant is bijective
    int wg = blockIdx.x;
    int qx = gridDim.x >> 3;
    int swz = (wg & 7) * qx + (wg >> 3);
    int mt = swz / 12, nt = swz - mt * 12;   // nt fastest: A-panel L2 reuse per XCD
    const u16* A = xb + (size_t)mt * 256 * 1024;
    const u16* B = wt + (size_t)nt * 256 * 1024;
    int tid = threadIdx.x;
    f32x4 acc[8][4] = {};
    gemm_block_256(A, 1024, B, 1024, 16, lds, tid, acc);
    int lane = tid & 63, wv = tid >> 6;
    int wm = wv >> 2, wn = wv & 3;
    int r0 = (lane >> 4) << 2, c0 = lane & 15;
    size_t mbase = (size_t)mt * 256 + wm * 128;
    int nbase = nt * 256 + wn * 64;
#pragma unroll
    for (int i = 0; i < 8; ++i)
#pragma unroll
        for (int j = 0; j < 4; ++j) {
            int col = nbase + j * 16 + c0;
            float scale = (col < 1024) ? 0.03125f : 1.0f;  // fold 1/sqrt(1024) into Q
#pragma unroll
            for (int r = 0; r < 4; ++r) {
                size_t row = mbase + i * 16 + r0 + r;
                qkv[row * (size_t)N_QKV + col] = f32_to_bf16(acc[i][j][r] * scale);
            }
        }
}

// ---------------- kernel 4: transpose V -> Vt [b][d][m] ----------------
__global__ __launch_bounds__(256) void transpose_v_kernel(const u16* __restrict__ qkv,
                                                          u16* __restrict__ vt) {
    __shared__ __align__(16) u16 tile[64][80];
    int m0 = blockIdx.x * 64, d0 = blockIdx.y * 64, b = blockIdx.z;
    const u16* src = qkv + (size_t)b * SEQ * N_QKV + 2048;  // V columns
    for (int g = threadIdx.x; g < 512; g += 256) {
        int r = g >> 3, c = (g & 7) << 3;
        *(u32x4*)&tile[r][c] = *(const u32x4*)(src + (size_t)(m0 + r) * N_QKV + d0 + c);
    }
    __syncthreads();
    u16* dst = vt + (size_t)b * DIM * SEQ;
    for (int g = threadIdx.x; g < 512; g += 256) {
        int dr = g >> 3, mc = (g & 7) << 3;
        __align__(16) u16 tmp[8];
#pragma unroll
        for (int i = 0; i < 8; ++i) tmp[i] = tile[mc + i][dr];
        *(u32x4*)(dst + (size_t)(d0 + dr) * SEQ + m0 + mc) = *(const u32x4*)tmp;
    }
}

// ---------------- kernel 5: S = Q . K^T, triangular 256-tile grid, bf16 out ----------------
__global__ __launch_bounds__(512, 2) void gemm_scores_kernel(const u16* __restrict__ qkv,
                                                             u16* __restrict__ S) {
    __shared__ __align__(16) u16 lds[8 * UNIT];
    int t = blockIdx.x;      // 0..35 triangular index over 8x8 256-tiles
    int b = blockIdx.y;
    // bounded integer triangular decomposition (no FP, <= 7 iterations)
    int ntile = 0;
#pragma unroll
    for (int it = 1; it < 8; ++it)
        if ((it * (it + 1)) / 2 <= t) ntile = it;
    int mtile = t - (ntile * (ntile + 1)) / 2;   // 0 <= mtile <= ntile
    const u16* A = qkv + (size_t)b * SEQ * N_QKV + (size_t)ntile * 256 * N_QKV;        // Q rows
    const u16* B = qkv + (size_t)b * SEQ * N_QKV + (size_t)mtile * 256 * N_QKV + 1024; // K rows
    int tid = threadIdx.x;
    f32x4 acc[8][4] = {};
    gemm_block_256(A, N_QKV, B, N_QKV, 16, lds, tid, acc);
    u16* out = S + (size_t)b * SEQ * SEQ + (size_t)ntile * 256 * SEQ + (size_t)mtile * 256;
    int lane = tid & 63, wv = tid >> 6;
    int wm = wv >> 2, wn = wv & 3;
    int r0 = (lane >> 4) << 2, c0 = lane & 15;
#pragma unroll
    for (int i = 0; i < 8; ++i)
#pragma unroll
        for (int j = 0; j < 4; ++j) {
            int col = wn * 64 + j * 16 + c0;
#pragma unroll
            for (int r = 0; r < 4; ++r) {
                int row = wm * 128 + i * 16 + r0 + r;
                out[(size_t)row * SEQ + col] = f32_to_bf16(acc[i][j][r]);
            }
        }
}

// ---------------- kernel 6: row softmax over bf16 S, in-place, register-resident ----
__global__ __launch_bounds__(256) void softmax_kernel(u16* __restrict__ SP) {
    int gr = blockIdx.x;
    int n = gr & 2047;
    u16* s = SP + (size_t)gr * SEQ;
    __shared__ float red[4];
    int t = threadIdx.x;
    int base = t << 3;
    int len = n + 1;
    float v[8];
    float lmax = -3.0e38f;
    if (base < len) {
        u32x4 raw = *(const u32x4*)(s + base);
        const u16* h = (const u16*)&raw;
#pragma unroll
        for (int i = 0; i < 8; ++i) {
            v[i] = (base + i < len) ? bf16_to_f32(h[i]) : -3.0e38f;
            lmax = fmaxf(lmax, v[i]);
        }
    } else {
#pragma unroll
        for (int i = 0; i < 8; ++i) v[i] = -3.0e38f;
    }
#pragma unroll
    for (int off = 32; off; off >>= 1) lmax = fmaxf(lmax, __shfl_xor(lmax, off, 64));
    if ((t & 63) == 0) red[t >> 6] = lmax;
    __syncthreads();
    float gmax = fmaxf(fmaxf(red[0], red[1]), fmaxf(red[2], red[3]));
    __syncthreads();   // everyone has gmax before red is reused
    float lsum = 0.f;
#pragma unroll
    for (int i = 0; i < 8; ++i) {
        float e = __expf(v[i] - gmax);   // masked lanes -> exp(-huge) = 0
        v[i] = e;
        lsum += e;
    }
#pragma unroll
    for (int off = 32; off; off >>= 1) lsum += __shfl_xor(lsum, off, 64);
    if ((t & 63) == 0) red[t >> 6] = lsum;
    __syncthreads();
    float inv = 1.0f / (red[0] + red[1] + red[2] + red[3]);
    __align__(16) u16 o[8];
#pragma unroll
    for (int i = 0; i < 8; ++i) o[i] = f32_to_bf16(v[i] * inv);  // masked lanes write 0
    *(u32x4*)(s + base) = *(const u32x4*)o;
}

// ---------------- kernel 7: O = P . V (via Vt), causal K truncation, 256^2 ----------------
// ntile reversed so the longest blocks (KT=32) dispatch first (tail balance).
__global__ __launch_bounds__(512, 2) void gemm_out_kernel(const u16* __restrict__ P,
                                                          const u16* __restrict__ vt,
                                                          float* __restrict__ O) {
    __shared__ __align__(16) u16 lds[8 * UNIT];
    int dt = blockIdx.x, b = blockIdx.z;
    int ntile = (SEQ / 256 - 1) - blockIdx.y;
    const u16* A = P + (size_t)b * SEQ * SEQ + (size_t)ntile * 256 * SEQ;
    const u16* B = vt + (size_t)b * DIM * SEQ + (size_t)dt * 256 * SEQ;
    int tid = threadIdx.x;
    f32x4 acc[8][4] = {};
    int KT = (ntile + 1) * 4;  // keys beyond (ntile+1)*256 have P == 0
    gemm_block_256(A, SEQ, B, SEQ, KT, lds, tid, acc);
    float* out = O + (size_t)b * SEQ * DIM + (size_t)ntile * 256 * DIM + (size_t)dt * 256;
    int lane = tid & 63, wv = tid >> 6;
    int wm = wv >> 2, wn = wv & 3;
    int r0 = (lane >> 4) << 2, c0 = lane & 15;
#pragma unroll
    for (int i = 0; i < 8; ++i)
#pragma unroll
        for (int j = 0; j < 4; ++j) {
            int col = wn * 64 + j * 16 + c0;
#pragma unroll
            for (int r = 0; r < 4; ++r) {
                int row = wm * 128 + i * 16 + r0 + r;
                out[(size_t)row * DIM + col] = acc[i][j][r];
            }
        }
}

extern "C" void kernel_launch(void* const* d_in, const int* in_sizes, int n_in,
                              void* d_out, int out_size, void* d_ws, size_t ws_size,
                              hipStream_t stream) {
    const float* x = (const float*)d_in[0];
    const float* wq = (const float*)d_in[1];
    const float* wk = (const float*)d_in[2];
    const float* wv = (const float*)d_in[3];
    char* ws = (char*)d_ws;
    u16* qkv = (u16*)(ws + OFF_QKV);
    u16* vt = (u16*)(ws + OFF_VT);
    u16* xb = (u16*)(ws + OFF_XB);
    u16* wt = (u16*)(ws + OFF_WT);
    u16* S = (u16*)(ws + OFF_S);   // aliases xb/wt region (dead by then)
    float* O = (float*)d_out;

    cast_x_kernel<<<M_TOT * DIM / 4 / 256, 256, 0, stream>>>(x, xb);
    transpose_w_kernel<<<dim3(16, 16, 3), 256, 0, stream>>>(wq, wk, wv, wt);
    gemm_qkv_kernel<<<(M_TOT / 256) * (N_QKV / 256), 512, 0, stream>>>(xb, wt, qkv);
    transpose_v_kernel<<<dim3(SEQ / 64, DIM / 64, BATCH), 256, 0, stream>>>(qkv, vt);
    gemm_scores_kernel<<<dim3(36, BATCH), 512, 0, stream>>>(qkv, S);
    softmax_kernel<<<BATCH * SEQ, 256, 0, stream>>>(S);
    gemm_out_kernel<<<dim3(DIM / 256, SEQ / 256, BATCH), 512, 0, stream>>>(S, vt, O);
}